// Round 3
// baseline (459.673 us; speedup 1.0000x reference)
//
#include <hip/hip_runtime.h>
#include <math.h>

#define TLEN 96000
#define NFFT 640
#define HOP  320
#define NF   321
#define NT   301
#define FT   (NF * NT)   // 96621

#define NCOL  4816       // 16 signals * 301 frames
#define NCOLP 4864       // padded to 19*256
#define CSTR  4864       // C column stride
#define CROWS 656        // 336 (E region) + 320 (O region)

#define TWO_PI_F 6.28318530717958647692f

typedef __attribute__((ext_vector_type(8))) short bfrag;
typedef __attribute__((ext_vector_type(4))) float f32x4;

__device__ inline short f2bf(float x) {   // RNE float->bf16
    unsigned u = __float_as_uint(x);
    u += 0x7fffu + ((u >> 16) & 1u);
    return (short)(u >> 16);
}

// ---------------------------------------------------------------------------
// K0a: fold + window x into bf16 B-matrices, transposed for fragment loads.
// FEt/FOt: [NCOLP][320] bf16, row c = s*301 + f, col n = window pos 0..319.
// fe = v(n)*w(n) + v(n+320)*w(n+320);  fo = difference.  Pad rows -> 0.
// ---------------------------------------------------------------------------
__global__ __launch_bounds__(320) void k_fold(const float* __restrict__ x,
                                              short* __restrict__ FEt,
                                              short* __restrict__ FOt) {
    const int c = blockIdx.x;     // 0..4863
    const int n = threadIdx.x;    // 0..319
    short e = 0, o = 0;
    if (c < NCOL) {
        const int s = c / NT;
        const int f = c % NT;
        const float* sig = x + (size_t)s * TLEN;
        const int p0 = f * HOP + n - HOP;
        const int p1 = p0 + HOP;
        const float cw = cosf((TWO_PI_F / NFFT) * (float)n);
        float v0 = (p0 >= 0) ? sig[p0] : 0.0f;            // p0 < TLEN always (f<=300)
        float v1 = (p1 < TLEN) ? sig[p1] : 0.0f;
        v0 *= (0.5f - 0.5f * cw);
        v1 *= (0.5f + 0.5f * cw);
        e = f2bf(v0 + v1);
        o = f2bf(v0 - v1);
    }
    FEt[(size_t)c * 320 + n] = e;
    FOt[(size_t)c * 320 + n] = o;
}

// ---------------------------------------------------------------------------
// K0b: twiddle matrices (bf16).  Ae[336][320], Ao[336][320].
// Ae row m: m<161 -> cos(2pi*m*n/320); 161<=m<322 -> -sin(2pi*(m-161)*n/320); pad 0.
// Ao row m: m<160 -> cos(2pi*(2m+1)*n/640); 160<=m<320 -> -sin(...); pad 0.
// Integer-mod argument reduction keeps sincosf accurate.
// ---------------------------------------------------------------------------
__global__ __launch_bounds__(320) void k_twid(short* __restrict__ Ae,
                                              short* __restrict__ Ao) {
    const int m = blockIdx.x;     // 0..671: 0..335 -> Ae, 336..671 -> Ao
    const int n = threadIdx.x;
    float val = 0.0f;
    if (m < 336) {
        if (m < 161) {
            const int r = (m * n) % 320;
            val = cosf((TWO_PI_F / 320.0f) * (float)r);
        } else if (m < 322) {
            const int r = ((m - 161) * n) % 320;
            val = -sinf((TWO_PI_F / 320.0f) * (float)r);
        }
        Ae[(size_t)m * 320 + n] = f2bf(val);
    } else {
        const int mm = m - 336;
        if (mm < 160) {
            const int r = ((2 * mm + 1) * n) % 640;
            val = cosf((TWO_PI_F / 640.0f) * (float)r);
        } else if (mm < 320) {
            const int r = ((2 * (mm - 160) + 1) * n) % 640;
            val = -sinf((TWO_PI_F / 640.0f) * (float)r);
        }
        Ao[(size_t)mm * 320 + n] = f2bf(val);
    }
}

// ---------------------------------------------------------------------------
// K1: DFT-as-GEMM (bf16 MFMA, LDS-free; A/B frags straight from L2).
// C[m][c] fp32: rows 0..321 = even bins (re 0..160, im 161..321, at rows+0),
// rows 336..655 = odd bins (re 336..495, im 496..655).
// Block: 256 thr = 4 waves; wave tile 16(m) x 64(c); block tile 16 x 256.
// ---------------------------------------------------------------------------
__global__ __launch_bounds__(256) void k_dftmm(const short* __restrict__ Ae,
                                               const short* __restrict__ Ao,
                                               const short* __restrict__ FEt,
                                               const short* __restrict__ FOt,
                                               float* __restrict__ C) {
    const int nt = blockIdx.x;    // 0..18
    const int mt = blockIdx.y;    // 0..40 (0..20 = E, 21..40 = O)
    const bool isE = (mt < 21);
    const int m0 = (isE ? mt : mt - 21) * 16;
    const short* A = isE ? Ae : Ao;
    const short* B = isE ? FEt : FOt;
    const int crow0 = isE ? 0 : 336;

    const int wave = threadIdx.x >> 6;
    const int lane = threadIdx.x & 63;
    const int q    = lane & 15;
    const int quad = lane >> 4;
    const int cbase = nt * 256 + wave * 64;

    const short* Arow = A + (size_t)(m0 + q) * 320 + quad * 8;
    const short* Brow = B + (size_t)(cbase + q) * 320 + quad * 8;

    f32x4 acc0 = {0.f,0.f,0.f,0.f}, acc1 = acc0, acc2 = acc0, acc3 = acc0;
#pragma unroll
    for (int kk = 0; kk < 320; kk += 32) {
        const bfrag a  = *(const bfrag*)(Arow + kk);
        const bfrag b0 = *(const bfrag*)(Brow + kk);
        const bfrag b1 = *(const bfrag*)(Brow + (size_t)16 * 320 + kk);
        const bfrag b2 = *(const bfrag*)(Brow + (size_t)32 * 320 + kk);
        const bfrag b3 = *(const bfrag*)(Brow + (size_t)48 * 320 + kk);
        acc0 = __builtin_amdgcn_mfma_f32_16x16x32_bf16(a, b0, acc0, 0, 0, 0);
        acc1 = __builtin_amdgcn_mfma_f32_16x16x32_bf16(a, b1, acc1, 0, 0, 0);
        acc2 = __builtin_amdgcn_mfma_f32_16x16x32_bf16(a, b2, acc2, 0, 0, 0);
        acc3 = __builtin_amdgcn_mfma_f32_16x16x32_bf16(a, b3, acc3, 0, 0, 0);
    }
    // D[row = quad*4 + r][col = lane&15], col offset f*16 per fragment
    float* Cb = C + (size_t)(crow0 + m0 + quad * 4) * CSTR + cbase + q;
#pragma unroll
    for (int r = 0; r < 4; ++r) {
        Cb[(size_t)r * CSTR +  0] = acc0[r];
        Cb[(size_t)r * CSTR + 16] = acc1[r];
        Cb[(size_t)r * CSTR + 32] = acc2[r];
        Cb[(size_t)r * CSTR + 48] = acc3[r];
    }
}

// ---------------------------------------------------------------------------
// K2: STFT of ref_g (batch 0) via fp32 Goertzel (audio-path precision).
// ---------------------------------------------------------------------------
__global__ __launch_bounds__(192) void k_stft_ref(const float* __restrict__ ref_g,
                                                  float2* __restrict__ refS) {
    const int f   = blockIdx.x;   // 0..300
    const int tid = threadIdx.x;

    __shared__ __align__(16) float2 ff[320];
    for (int n = tid; n < 320; n += 192) {
        const int p0 = f * HOP + n - HOP;
        const int p1 = p0 + HOP;
        const float cw = cosf((TWO_PI_F / NFFT) * (float)n);
        float v0 = (p0 >= 0) ? ref_g[p0] : 0.0f;
        float v1 = (p1 < TLEN) ? ref_g[p1] : 0.0f;
        v0 *= (0.5f - 0.5f * cw);
        v1 *= (0.5f + 0.5f * cw);
        float2 o; o.x = v0 + v1; o.y = v0 - v1;
        ff[n] = o;
    }
    __syncthreads();

    if (tid < 161) {
        const int ke = 2 * tid;
        const int ko = ke + 1;
        const float we = (TWO_PI_F / NFFT) * (float)ke;
        const float wo = (TWO_PI_F / NFFT) * (float)ko;
        const float c2e = 2.0f * cosf(we);
        const float c2o = 2.0f * cosf(wo);
        float se1 = 0.0f, se2 = 0.0f, so1 = 0.0f, so2 = 0.0f;
#pragma unroll 8
        for (int n = 0; n < 320; ++n) {
            const float2 v = ff[n];
            const float te = fmaf(c2e, se1, v.x - se2); se2 = se1; se1 = te;
            const float to = fmaf(c2o, so1, v.y - so2); so2 = so1; so1 = to;
        }
        float sE, cE; sincosf(we, &sE, &cE);
        float sO, cO; sincosf(wo, &sO, &cO);
        float2 Xe, Xo;
        Xe.x = cE * se1 - se2;   Xe.y = sE * se1;
        Xo.x = -(cO * so1 - so2); Xo.y = -(sO * so1);
        refS[(size_t)ke * NT + f] = Xe;
        if (ko < 320) refS[(size_t)ko * NT + f] = Xo;
    }
}

// ---------------------------------------------------------------------------
// K3: covariance features from C.  One thread per (b,k,t): 16 loads -> 74 stores.
// ---------------------------------------------------------------------------
__global__ __launch_bounds__(64) void k_cov(const float* __restrict__ C,
                                            float* __restrict__ feats) {
    const int t = blockIdx.x * 64 + threadIdx.x;
    if (t >= NT) return;
    const int bk = blockIdx.y;           // b*321 + k
    const int b = bk / NF;
    const int k = bk % NF;
    const int h = k >> 1;
    const int m_re = (k & 1) ? 336 + h : h;
    const int m_im = (k & 1) ? 496 + h : 161 + h;
    const float* rr = C + (size_t)m_re * CSTR + b * 8 * NT + t;
    const float* ri = C + (size_t)m_im * CSTR + b * 8 * NT + t;
    float ar[8], ai[8];
#pragma unroll
    for (int s = 0; s < 8; ++s) {
        ar[s] = rr[s * NT];
        ai[s] = ri[s * NT];
    }
    float* fb = feats + (size_t)b * 74 * FT + (size_t)k * NT + t;
    int p = 0;
#pragma unroll
    for (int i = 0; i < 8; ++i) {
#pragma unroll
        for (int j = i; j < 8; ++j) {
            fb[(size_t)(2 * p)     * FT] = ar[i] * ar[j] + ai[i] * ai[j];
            fb[(size_t)(2 * p + 1) * FT] = ai[i] * ar[j] - ar[i] * ai[j];
            ++p;
        }
    }
    fb[(size_t)72 * FT] = ar[3];   // REF_CH = 3
    fb[(size_t)73 * FT] = ai[3];
}

// ---------------------------------------------------------------------------
// K4: deep filtering, batch 0 only (unchanged).
// ---------------------------------------------------------------------------
__global__ void k_dfilter(const float2* __restrict__ rtf,
                          const float2* __restrict__ refS,
                          float2* __restrict__ est) {
    int idx = blockIdx.x * blockDim.x + threadIdx.x;
    if (idx >= 7 * FT) return;
    const int t = idx % NT;
    const int f = (idx / NT) % NF;
    const int m = idx / FT;
    float er = 0.0f, ei = 0.0f;
#pragma unroll
    for (int ki = 0; ki < 3; ++ki) {
        const int ff = f + ki - 1;
#pragma unroll
        for (int kj = 0; kj < 9; ++kj) {
            const int tt = t + kj - 4;
            float pr = 0.0f, pi = 0.0f;
            if ((unsigned)ff < (unsigned)NF && (unsigned)tt < (unsigned)NT) {
                const float2 p = refS[(size_t)ff * NT + tt];
                pr = p.x; pi = p.y;
            }
            const float2 r = rtf[(size_t)(((m * 3 + ki) * 9 + kj) * NF + f) * NT + t];
            er = fmaf(r.x, pr, er); er = fmaf(-r.y, pi, er);
            ei = fmaf(r.x, pi, ei); ei = fmaf( r.y, pr, ei);
        }
    }
    float2 o; o.x = er; o.y = ei;
    est[idx] = o;
}

// ---------------------------------------------------------------------------
// K5: per-frame irfft(640)*win via Goertzel over k (unchanged).
// ---------------------------------------------------------------------------
__global__ __launch_bounds__(320) void k_iframes(const float2* __restrict__ est,
                                                 float* __restrict__ frames) {
    const int f   = blockIdx.x;
    const int m   = blockIdx.y;
    const int tid = threadIdx.x;
    __shared__ __align__(16) float2 X[322];
    for (int k = tid; k < NF; k += 320)
        X[k] = est[((size_t)m * NF + k) * NT + f];
    if (tid == 0) { float2 z; z.x = 0.0f; z.y = 0.0f; X[321] = z; }
    __syncthreads();

    const int n = tid;
    float sp, cp; sincosf((TWO_PI_F / NFFT) * (float)n, &sp, &cp);
    const float c2p = cp * cp - sp * sp;
    const float s2p = 2.0f * sp * cp;
    const float c2  = 2.0f * c2p;

    float er1 = 0.0f, er2 = 0.0f, ei1 = 0.0f, ei2 = 0.0f;
    float or1 = 0.0f, or2 = 0.0f, oi1 = 0.0f, oi2 = 0.0f;
    const float4* Xp = (const float4*)X;
#pragma unroll 4
    for (int j = 0; j < 160; ++j) {
        const float4 v = Xp[j];
        const float t0 = fmaf(c2, er1, v.x - er2); er2 = er1; er1 = t0;
        const float t1 = fmaf(c2, ei1, v.y - ei2); ei2 = ei1; ei1 = t1;
        const float t2 = fmaf(c2, or1, v.z - or2); or2 = or1; or1 = t2;
        const float t3 = fmaf(c2, oi1, v.w - oi2); oi2 = oi1; oi1 = t3;
    }
    {
        const float4 v = Xp[160];
        const float t0 = fmaf(c2, er1, v.x - er2); er2 = er1; er1 = t0;
        const float t1 = fmaf(c2, ei1, v.y - ei2); ei2 = ei1; ei1 = t1;
    }
    const float PEbr = c2p * er1 + s2p * ei1 - er2;
    const float PEbi = c2p * ei1 - s2p * er1 - ei2;
    const float PObr = c2p * or1 + s2p * oi1 - or2;
    const float PObi = c2p * oi1 - s2p * or1 - oi2;

    float sr, crr; sincosf((TWO_PI_F / 320.0f) * (float)n, &sr, &crr);
    const float sgn  = (n & 1) ? -1.0f : 1.0f;
    const float RePE = sgn * (crr * PEbr - sr * PEbi);
    const float RePO = sgn * (cp * PObr - sp * PObi);

    const float base = X[0].x + sgn * X[320].x;
    const float y1 = 2.0f * (RePE + RePO) - base;
    const float y2 = 2.0f * (RePE - RePO) - base;

    const float w0 = 0.5f - 0.5f * cp;
    const float w1 = 0.5f + 0.5f * cp;
    const float inv = 1.0f / NFFT;
    float* fb = frames + ((size_t)m * NT + f) * NFFT;
    fb[n]       = y1 * inv * w0;
    fb[n + 320] = y2 * inv * w1;
}

// ---------------------------------------------------------------------------
// K6: overlap-add + wsum normalization + interleaved [t][c] output (unchanged).
// ---------------------------------------------------------------------------
__global__ void k_ola(const float* __restrict__ frames,
                      const float* __restrict__ ref_g,
                      float* __restrict__ out0) {
    int idx = blockIdx.x * blockDim.x + threadIdx.x;
    if (idx >= 8 * TLEN) return;
    const int c = idx & 7;
    const int t = idx >> 3;
    float o;
    if (c == 3) {
        o = ref_g[t];
    } else {
        const int m  = (c < 3) ? c : (c - 1);
        const int f1 = t / HOP + 1;
        const int n1 = t % HOP;
        const float a = frames[((size_t)m * NT + f1)     * NFFT + n1];
        const float b = frames[((size_t)m * NT + f1 - 1) * NFFT + n1 + 320];
        const float cw = cosf((TWO_PI_F / NFFT) * (float)n1);
        const float w0 = 0.5f - 0.5f * cw;
        const float w1 = 0.5f + 0.5f * cw;
        float ws = w0 * w0 + w1 * w1;
        ws = (ws > 1e-11f) ? ws : 1.0f;
        o = (a + b) / ws;
    }
    out0[idx] = o;
}

extern "C" void kernel_launch(void* const* d_in, const int* in_sizes, int n_in,
                              void* d_out, int out_size, void* d_ws, size_t ws_size,
                              hipStream_t stream) {
    const float* x     = (const float*)d_in[0];   // [2,8,96000]
    const float* rtf   = (const float*)d_in[1];   // [2,7,3,9,321,301,2]
    const float* ref_g = (const float*)d_in[2];   // [2,1,96000]

    float* out0  = (float*)d_out;                     // [96000,8]
    float* feats = (float*)d_out + (size_t)8 * TLEN;  // [2,74,321,301]

    // workspace carve-up (all 64B-aligned)
    char* w = (char*)d_ws;
    auto carve = [&](size_t bytes) {
        char* p = w;
        w += (bytes + 63) & ~(size_t)63;
        return p;
    };
    float*  Cm     = (float*)carve((size_t)CROWS * CSTR * 4);   // 12.8 MB
    short*  FEt    = (short*)carve((size_t)NCOLP * 320 * 2);    // 3.1 MB
    short*  FOt    = (short*)carve((size_t)NCOLP * 320 * 2);    // 3.1 MB
    short*  Ae     = (short*)carve((size_t)336 * 320 * 2);
    short*  Ao     = (short*)carve((size_t)336 * 320 * 2);
    float2* refS   = (float2*)carve((size_t)FT * 8);
    float2* est    = (float2*)carve((size_t)7 * FT * 8);
    float*  frames = (float*)carve((size_t)7 * NT * NFFT * 4);

    k_fold<<<NCOLP, 320, 0, stream>>>(x, FEt, FOt);
    k_twid<<<672, 320, 0, stream>>>(Ae, Ao);
    k_stft_ref<<<NT, 192, 0, stream>>>(ref_g, refS);
    k_dftmm<<<dim3(19, 41), 256, 0, stream>>>(Ae, Ao, FEt, FOt, Cm);
    k_cov<<<dim3(5, 2 * NF), 64, 0, stream>>>(Cm, feats);
    {
        const int total = 7 * FT;
        k_dfilter<<<(total + 255) / 256, 256, 0, stream>>>(
            (const float2*)rtf, refS, est);
    }
    k_iframes<<<dim3(NT, 7), 320, 0, stream>>>(est, frames);
    {
        const int total = 8 * TLEN;
        k_ola<<<(total + 255) / 256, 256, 0, stream>>>(frames, ref_g, out0);
    }
}